// Round 7
// baseline (125.790 us; speedup 1.0000x reference)
//
#include <hip/hip_runtime.h>
#include <hip/hip_bf16.h>

#define B_    2
#define SQ_   2048
#define SK_   2048
#define NH_   16
#define DH_   64
#define WIN_  256
#define NEG_  -30000.0f

typedef __bf16 bf16_t;
typedef bf16_t bf16x8 __attribute__((ext_vector_type(8)));
typedef bf16_t bf16x4 __attribute__((ext_vector_type(4)));
typedef float  f32x4  __attribute__((ext_vector_type(4)));
typedef short  s16x4  __attribute__((ext_vector_type(4)));
typedef unsigned int u32;

// bf16 images in workspace, XOR swizzle baked into the GLOBAL layout
// (16B-chunk index ^= row&7), so tile staging is a linear global_load_lds copy
// and LDS reads apply the same XOR (T2 / m173 pattern):
//   K  [bh][key][d]: elem = bh*131072 + key*64 + ((c ^ (key&7))<<3) + (d&7)
//   V^T[bh][d][key]: elem = 4194304 + bh*131072 + d*2048
//                           + (((g&~7)|((g&7)^(d&7)))<<3) + (key&7),  g = key>>3
#define KE_BH 131072
#define VT_E  4194304

#define GLOAD_LDS16(g, l)                                                      \
  __builtin_amdgcn_global_load_lds(                                            \
      (const __attribute__((address_space(1))) u32*)(g),                       \
      (__attribute__((address_space(3))) u32*)(l), 16, 0, 0)

// ---------------- prep: f32 KV -> swizzled bf16 K / V^T images ----------------
__global__ __launch_bounds__(256)
void kv_prep(const float* __restrict__ kvg, bf16_t* __restrict__ wse) {
  const int t   = blockIdx.x * 256 + threadIdx.x;   // 524288 threads total
  const int c   = t & 7;                 // 16B chunk = 8 d-elements
  const int key = (t >> 3) & (SK_ - 1);
  const int bh  = t >> 14;               // 0..31
  const int b   = bh >> 4, h = bh & 15;

  const size_t base =
      ((((size_t)b * SK_ + key) * 2) * NH_ + h) * (size_t)DH_ + (size_t)(c * 8);

  // K chunk: one contiguous 16B store at the swizzled chunk slot
  {
    f32x4 a0 = *(const f32x4*)(kvg + base);
    f32x4 a1 = *(const f32x4*)(kvg + base + 4);
    bf16x8 w;
#pragma unroll
    for (int i = 0; i < 4; ++i) { w[i] = (bf16_t)a0[i]; w[i + 4] = (bf16_t)a1[i]; }
    *(bf16x8*)(wse + (size_t)bh * KE_BH + key * 64 + ((c ^ (key & 7)) << 3)) = w;
  }
  // V^T: 8 scalar stores, one per d-row (transpose; swizzle per destination row)
  {
    const float* vsrc = kvg + base + NH_ * DH_;
    const int g = key >> 3, kw = key & 7, gh = g & ~7, gl = g & 7;
    bf16_t* vdst = wse + VT_E + (size_t)bh * KE_BH + kw;
#pragma unroll
    for (int j = 0; j < 8; ++j) {
      const int d = c * 8 + j;          // d & 7 == j
      vdst[(size_t)d * 2048 + ((gh | (gl ^ j)) << 3)] = (bf16_t)vsrc[j];
    }
  }
}

// ------------------------------- main kernel ---------------------------------
__global__ __launch_bounds__(256, 4)
void fa_fwd(const float* __restrict__ qg, const bf16_t* __restrict__ wse,
            float* __restrict__ outg) {
  const int tid  = threadIdx.x;
  const int wid  = tid >> 6;      // 0..3, each wave owns 16 q-rows
  const int lane = tid & 63;
  const int quad = lane >> 4;
  const int li   = lane & 15;
  const int lk   = li & 7;

  const int bid = blockIdx.x;
  const int qb  = bid >> 5;   // 32 q-blocks of 64 rows
  const int bh  = bid & 31;   // same bh -> same XCD (kv L2 locality)
  const int b   = bh >> 4;
  const int h   = bh & 15;

  const int q0b = qb * 64;
  const int q0  = q0b + wid * 16;

  __shared__ __align__(16) bf16_t sK[2][4096];   // K tile image (swizzled)
  __shared__ __align__(16) bf16_t sV[2][4096];   // V^T tile image (swizzled)

  const bf16_t* kbh = wse + (size_t)bh * KE_BH;
  const bf16_t* vbh = wse + VT_E + (size_t)bh * KE_BH;

  // ---- Q fragments (16 rows), scale * log2(e) folded ----
  const float qscale = 0.125f * 1.44269504088896340736f;
  const float* qrow = qg + ((size_t)((b * SQ_ + q0 + li) * NH_ + h)) * DH_;
  bf16x8 qfrag[2];
#pragma unroll
  for (int c = 0; c < 2; ++c) {
    f32x4 a0 = *(const f32x4*)(qrow + c * 32 + quad * 8);
    f32x4 a1 = *(const f32x4*)(qrow + c * 32 + quad * 8 + 4);
#pragma unroll
    for (int i = 0; i < 4; ++i) {
      qfrag[c][i]     = (bf16_t)(a0[i] * qscale);
      qfrag[c][i + 4] = (bf16_t)(a1[i] * qscale);
    }
  }

  f32x4 oacc[4];
#pragma unroll
  for (int t = 0; t < 4; ++t) { f32x4 z = {0.f, 0.f, 0.f, 0.f}; oacc[t] = z; }
  float m = NEG_, l = 0.f;   // l is a per-lane PARTIAL (reduced in epilogue)

  // block-uniform 64-aligned key range
  int klo = q0b - WIN_; if (klo < 0) klo = 0;
  int khi = q0b + 63 + WIN_ + 1; if (khi > SK_) khi = SK_;
  const int nt = (khi - klo + 63) >> 6;

  // staging constants: 4 x global_load_lds(16B) per thread per tile,
  // lane-linear LDS destinations, pre-swizzled global sources
  const int tid8 = tid * 8;                              // LDS elem offset
  const int vs0  = (tid >> 3) * 2048 + (tid & 7) * 8;    // V src: d*2048 + sc*8

  // ---- prologue: stage tile 0 -> buf 0 (async), then barrier-drain ----
  GLOAD_LDS16(kbh + klo * 64 + tid8,        &sK[0][tid8]);
  GLOAD_LDS16(kbh + klo * 64 + 2048 + tid8, &sK[0][2048 + tid8]);
  GLOAD_LDS16(vbh + klo + vs0,              &sV[0][tid8]);
  GLOAD_LDS16(vbh + klo + vs0 + 65536,      &sV[0][2048 + tid8]);
  __syncthreads();

  int buf = 0;
  for (int t = 0; t < nt; ++t) {
    const int kk = klo + t * 64;
    // issue next tile's async copies; the compute below covers their latency,
    // and __syncthreads' vmcnt(0) drain completes them before the buffer flip
    if (t + 1 < nt) {
      const int kn = kk + 64;
      GLOAD_LDS16(kbh + kn * 64 + tid8,        &sK[buf ^ 1][tid8]);
      GLOAD_LDS16(kbh + kn * 64 + 2048 + tid8, &sK[buf ^ 1][2048 + tid8]);
      GLOAD_LDS16(vbh + kn + vs0,              &sV[buf ^ 1][tid8]);
      GLOAD_LDS16(vbh + kn + vs0 + 65536,      &sV[buf ^ 1][2048 + tid8]);
    }

    // ---- compute only if this tile intersects the wave's window ----
    if (kk + 63 >= q0 - WIN_ && kk <= q0 + 15 + WIN_) {
      // S^T = K . Q^T : 4 key subtiles, D=64 as two K=32 chunks
      f32x4 sc[4];
      __builtin_amdgcn_s_setprio(1);
#pragma unroll
      for (int s = 0; s < 4; ++s) {
        const int row = (s * 16 + li) * 64;
        bf16x8 kf0 = *(const bf16x8*)(&sK[buf][row + ((quad ^ lk) << 3)]);
        bf16x8 kf1 = *(const bf16x8*)(&sK[buf][row + (((quad + 4) ^ lk) << 3)]);
        f32x4 acc = {0.f, 0.f, 0.f, 0.f};
        acc = __builtin_amdgcn_mfma_f32_16x16x32_bf16(kf0, qfrag[0], acc, 0, 0, 0);
        acc = __builtin_amdgcn_mfma_f32_16x16x32_bf16(kf1, qfrag[1], acc, 0, 0, 0);
        sc[s] = acc;
      }
      __builtin_amdgcn_s_setprio(0);

      // window mask only on boundary tiles (wave-uniform branch)
      if (kk < q0 - 241 || kk > q0 + 193) {
        const int qa = q0 + li;
#pragma unroll
        for (int s = 0; s < 4; ++s)
#pragma unroll
          for (int r = 0; r < 4; ++r) {
            int key = kk + s * 16 + quad * 4 + r;
            unsigned dd = (unsigned)(key - qa + WIN_);
            if (dd > 2u * WIN_) sc[s][r] = NEG_;
          }
      }
      // local tile max (the defer ballot covers all lanes of every column)
      float tl = NEG_;
#pragma unroll
      for (int s = 0; s < 4; ++s)
        tl = fmaxf(tl, fmaxf(fmaxf(sc[s][0], sc[s][1]), fmaxf(sc[s][2], sc[s][3])));

      // T13 defer-max: skip rescale while max growth <= 8 (log2 domain)
      const bool defer = (__all(tl <= m + 8.0f) != 0);   // wave-uniform
      float mnew = m;
      if (!defer) {
        float tr = fmaxf(tl, __shfl_xor(tl, 16));
        tr = fmaxf(tr, __shfl_xor(tr, 32));
        mnew = fmaxf(m, tr);
      }

      // P stays in-lane: QK^T C-layout == 16x16x16 MFMA A-layout per key subtile
      float psum = 0.f;
      bf16x4 pa[4];
#pragma unroll
      for (int s = 0; s < 4; ++s) {
        float p0 = exp2f(sc[s][0] - mnew);
        float p1 = exp2f(sc[s][1] - mnew);
        float p2 = exp2f(sc[s][2] - mnew);
        float p3 = exp2f(sc[s][3] - mnew);
        psum += (p0 + p1) + (p2 + p3);
        pa[s][0] = (bf16_t)p0; pa[s][1] = (bf16_t)p1;
        pa[s][2] = (bf16_t)p2; pa[s][3] = (bf16_t)p3;
      }

      if (!defer) {
        const float alpha = exp2f(m - mnew);
        float al[4];
#pragma unroll
        for (int r = 0; r < 4; ++r) al[r] = __shfl(alpha, quad * 4 + r);
#pragma unroll
        for (int t2 = 0; t2 < 4; ++t2) {
          oacc[t2][0] *= al[0]; oacc[t2][1] *= al[1];
          oacc[t2][2] *= al[2]; oacc[t2][3] *= al[3];
        }
        l = l * alpha + psum;   // per-lane partial, column-uniform alpha
        m = mnew;
      } else {
        l += psum;
      }

      // O += P . V : K=16 MFMA per key subtile, V^T from swizzled LDS
      __builtin_amdgcn_s_setprio(1);
#pragma unroll
      for (int s = 0; s < 4; ++s) {
        const s16x4 pas = __builtin_bit_cast(s16x4, pa[s]);
        const int cA = 2 * s + (quad >> 1);   // tile-local 16B chunk of 8 keys
#pragma unroll
        for (int t2 = 0; t2 < 4; ++t2) {
          const int d = 16 * t2 + li;
          s16x4 vb = *(const s16x4*)(
              &sV[buf][d * 64 + ((cA ^ lk) << 3) + (quad & 1) * 4]);
          oacc[t2] = __builtin_amdgcn_mfma_f32_16x16x16bf16_1k(pas, vb, oacc[t2], 0, 0, 0);
        }
      }
      __builtin_amdgcn_s_setprio(0);
    }

    __syncthreads();   // single barrier: drains the async copies, flips buffers
    buf ^= 1;
  }

  // ---- epilogue: reduce the per-lane l partials, then normalize ----
  l += __shfl_xor(l, 16);
  l += __shfl_xor(l, 32);
  float rl[4];
#pragma unroll
  for (int r = 0; r < 4; ++r) {
    float lv = __shfl(l, quad * 4 + r);
    rl[r] = 1.0f / lv;
  }
  float* orow = outg + ((size_t)((b * SQ_ + q0) * NH_ + h)) * DH_;
#pragma unroll
  for (int t = 0; t < 4; ++t)
#pragma unroll
    for (int r = 0; r < 4; ++r)
      orow[(size_t)(quad * 4 + r) * (NH_ * DH_) + 16 * t + li] = oacc[t][r] * rl[r];
}

extern "C" void kernel_launch(void* const* d_in, const int* in_sizes, int n_in,
                              void* d_out, int out_size, void* d_ws, size_t ws_size,
                              hipStream_t stream) {
  (void)in_sizes; (void)n_in; (void)out_size; (void)ws_size;
  const float* q  = (const float*)d_in[0];
  const float* kv = (const float*)d_in[1];
  float* out = (float*)d_out;
  bf16_t* wse = (bf16_t*)d_ws;   // needs 16 MiB

  kv_prep<<<dim3(2048), 256, 0, stream>>>(kv, wse);
  fa_fwd<<<dim3(B_ * NH_ * (SQ_ / 64)), 256, 0, stream>>>(q, wse, out);
}

// Round 9
// 122.968 us; speedup vs baseline: 1.0230x; 1.0230x over previous
//
#include <hip/hip_runtime.h>
#include <hip/hip_bf16.h>

#define B_    2
#define SQ_   2048
#define SK_   2048
#define NH_   16
#define DH_   64
#define WIN_  256
#define NEG_  -30000.0f

typedef __bf16 bf16_t;
typedef bf16_t bf16x8 __attribute__((ext_vector_type(8)));
typedef bf16_t bf16x4 __attribute__((ext_vector_type(4)));
typedef float  f32x4  __attribute__((ext_vector_type(4)));
typedef short  s16x4  __attribute__((ext_vector_type(4)));
typedef unsigned int u32;

// bf16 images in workspace, XOR swizzle baked into the GLOBAL layout
// (16B-chunk index ^= row&7), so tile staging is a linear global_load_lds copy
// and LDS reads apply the same XOR (T2 / m173 pattern):
//   K  [bh][key][d]: elem = bh*131072 + key*64 + ((c ^ (key&7))<<3) + (d&7)
//   V^T[bh][d][key]: elem = 4194304 + bh*131072 + d*2048
//                           + (((g&~7)|((g&7)^(d&7)))<<3) + (key&7),  g = key>>3
#define KE_BH 131072
#define VT_E  4194304

#define GLOAD_LDS16(g, l)                                                      \
  __builtin_amdgcn_global_load_lds(                                            \
      (const __attribute__((address_space(1))) u32*)(g),                       \
      (__attribute__((address_space(3))) u32*)(l), 16, 0, 0)

// ---------------- prep: f32 KV -> swizzled bf16 K / V^T images ----------------
// one block per (bh, 64-key tile); all global stores are 16B vectors
__global__ __launch_bounds__(256)
void kv_prep(const float* __restrict__ kvg, bf16_t* __restrict__ wse) {
  __shared__ __align__(16) bf16_t sT[4096];   // V^T tile, image layout
  const int tid = threadIdx.x;
  const int bb  = blockIdx.x;          // bh*32 + kt
  const int bh  = bb >> 5, kt = bb & 31;
  const int b   = bh >> 4, h = bh & 15;   // FIX: h from bh (was bb & 15)

  const int skey = tid >> 2;           // 0..63
  const int sd0  = (tid & 3) * 16;     // 0,16,32,48
  const int key  = kt * 64 + skey;

  const float* src =
      kvg + ((((size_t)b * SK_ + key) * 2) * NH_ + h) * (size_t)DH_ + sd0;
  f32x4 ka[4], va[4];
#pragma unroll
  for (int i = 0; i < 4; ++i) {
    ka[i] = *(const f32x4*)(src + 4 * i);
    va[i] = *(const f32x4*)(src + NH_ * DH_ + 4 * i);
  }

  // K: two swizzled 16B stores
  bf16_t* kdst = wse + (size_t)bh * KE_BH + (size_t)key * 64;
#pragma unroll
  for (int hh = 0; hh < 2; ++hh) {
    bf16x8 w;
#pragma unroll
    for (int i = 0; i < 4; ++i) {
      w[i] = (bf16_t)ka[2 * hh][i]; w[i + 4] = (bf16_t)ka[2 * hh + 1][i];
    }
    const int c = (sd0 >> 3) + hh;
    *(bf16x8*)(kdst + ((c ^ (key & 7)) << 3)) = w;
  }

  // V: transpose into LDS using the tile-local image layout
  const int g = skey >> 3, kw = skey & 7;
#pragma unroll
  for (int j = 0; j < 16; ++j) {
    const int d = sd0 + j;
    sT[d * 64 + ((g ^ (d & 7)) << 3) + kw] = (bf16_t)va[j >> 2][j & 3];
  }
  __syncthreads();

  // copy-out: 2 x 16B per thread, contiguous
  const int dr = tid >> 2, rp = (tid & 3) * 16;
  bf16_t* vdst = wse + VT_E + (size_t)bh * KE_BH + (size_t)dr * 2048 + kt * 64 + rp;
  *(bf16x8*)(vdst)     = *(const bf16x8*)(&sT[dr * 64 + rp]);
  *(bf16x8*)(vdst + 8) = *(const bf16x8*)(&sT[dr * 64 + rp + 8]);
}

// ------------------------------- main kernel ---------------------------------
__global__ __launch_bounds__(256, 3)
void fa_fwd(const float* __restrict__ qg, const bf16_t* __restrict__ wse,
            float* __restrict__ outg) {
  const int tid  = threadIdx.x;
  const int wid  = tid >> 6;      // 0..3, each wave owns 16 q-rows
  const int lane = tid & 63;
  const int quad = lane >> 4;
  const int li   = lane & 15;
  const int lk   = li & 7;

  const int bid = blockIdx.x;
  const int qb  = bid >> 5;   // 32 q-blocks of 64 rows
  const int bh  = bid & 31;   // same bh -> same XCD (kv L2 locality)
  const int b   = bh >> 4;
  const int h   = bh & 15;

  const int q0b = qb * 64;
  const int q0  = q0b + wid * 16;

  // 3-buffer rotation: loads stay in flight for 2 full iterations
  __shared__ __align__(16) bf16_t sK[3][4096];   // K tile images (swizzled)
  __shared__ __align__(16) bf16_t sV[3][4096];   // V^T tile images (swizzled)

  const bf16_t* kbh = wse + (size_t)bh * KE_BH;
  const bf16_t* vbh = wse + VT_E + (size_t)bh * KE_BH;

  // ---- Q fragments (16 rows), scale * log2(e) folded ----
  const float qscale = 0.125f * 1.44269504088896340736f;
  const float* qrow = qg + ((size_t)((b * SQ_ + q0 + li) * NH_ + h)) * DH_;
  bf16x8 qfrag[2];
#pragma unroll
  for (int c = 0; c < 2; ++c) {
    f32x4 a0 = *(const f32x4*)(qrow + c * 32 + quad * 8);
    f32x4 a1 = *(const f32x4*)(qrow + c * 32 + quad * 8 + 4);
#pragma unroll
    for (int i = 0; i < 4; ++i) {
      qfrag[c][i]     = (bf16_t)(a0[i] * qscale);
      qfrag[c][i + 4] = (bf16_t)(a1[i] * qscale);
    }
  }

  f32x4 oacc[4];
#pragma unroll
  for (int t = 0; t < 4; ++t) { f32x4 z = {0.f, 0.f, 0.f, 0.f}; oacc[t] = z; }
  float m = NEG_, l = 0.f;   // l is a per-lane PARTIAL (reduced in epilogue)

  // block-uniform 64-aligned key range
  int klo = q0b - WIN_; if (klo < 0) klo = 0;
  int khi = q0b + 63 + WIN_ + 1; if (khi > SK_) khi = SK_;
  const int nt = (khi - klo + 63) >> 6;   // 5..9, block-uniform

  // staging: 4 x global_load_lds(16B) per thread per tile, lane-linear dests
  const int tid8 = tid * 8;
  const int vs0  = (tid >> 3) * 2048 + (tid & 7) * 8;

  bf16_t* k0 = sK[0]; bf16_t* k1 = sK[1]; bf16_t* k2 = sK[2];
  bf16_t* v0 = sV[0]; bf16_t* v1 = sV[1]; bf16_t* v2 = sV[2];

  auto stage_async = [&](int kt, bf16_t* kd, bf16_t* vd) {
    GLOAD_LDS16(kbh + kt * 64 + tid8,        kd + tid8);
    GLOAD_LDS16(kbh + kt * 64 + 2048 + tid8, kd + 2048 + tid8);
    GLOAD_LDS16(vbh + kt + vs0,              vd + tid8);
    GLOAD_LDS16(vbh + kt + vs0 + 65536,      vd + 2048 + tid8);
  };

  // ---- prologue: tiles 0,1 in flight; wait only for tile 0 ----
  stage_async(klo, k0, v0);
  stage_async(klo + 64, k1, v1);
  asm volatile("s_waitcnt vmcnt(4)" ::: "memory");
  __builtin_amdgcn_s_barrier();
  __builtin_amdgcn_sched_barrier(0);

  for (int t = 0; t < nt; ++t) {
    const int kk = klo + t * 64;
    if (t + 2 < nt) stage_async(klo + (t + 2) * 64, k2, v2);

    // ---- compute only if this tile intersects the wave's window ----
    if (kk + 63 >= q0 - WIN_ && kk <= q0 + 15 + WIN_) {
      // S^T = K . Q^T : 4 key subtiles, D=64 as two K=32 chunks
      f32x4 sc[4];
      __builtin_amdgcn_s_setprio(1);
#pragma unroll
      for (int s = 0; s < 4; ++s) {
        const int row = (s * 16 + li) * 64;
        bf16x8 kf0 = *(const bf16x8*)(&k0[row + ((quad ^ lk) << 3)]);
        bf16x8 kf1 = *(const bf16x8*)(&k0[row + (((quad + 4) ^ lk) << 3)]);
        f32x4 acc = {0.f, 0.f, 0.f, 0.f};
        acc = __builtin_amdgcn_mfma_f32_16x16x32_bf16(kf0, qfrag[0], acc, 0, 0, 0);
        acc = __builtin_amdgcn_mfma_f32_16x16x32_bf16(kf1, qfrag[1], acc, 0, 0, 0);
        sc[s] = acc;
      }
      __builtin_amdgcn_s_setprio(0);

      // window mask only on boundary tiles (wave-uniform branch)
      if (kk < q0 - 241 || kk > q0 + 193) {
        const int qa = q0 + li;
#pragma unroll
        for (int s = 0; s < 4; ++s)
#pragma unroll
          for (int r = 0; r < 4; ++r) {
            int key = kk + s * 16 + quad * 4 + r;
            unsigned dd = (unsigned)(key - qa + WIN_);
            if (dd > 2u * WIN_) sc[s][r] = NEG_;
          }
      }
      // local tile max (the defer ballot covers all lanes of every column)
      float tl = NEG_;
#pragma unroll
      for (int s = 0; s < 4; ++s)
        tl = fmaxf(tl, fmaxf(fmaxf(sc[s][0], sc[s][1]), fmaxf(sc[s][2], sc[s][3])));

      // T13 defer-max: skip rescale while max growth <= 8 (log2 domain)
      const bool defer = (__all(tl <= m + 8.0f) != 0);   // wave-uniform
      float mnew = m;
      if (!defer) {
        float tr = fmaxf(tl, __shfl_xor(tl, 16));
        tr = fmaxf(tr, __shfl_xor(tr, 32));
        mnew = fmaxf(m, tr);
      }

      // P stays in-lane: QK^T C-layout == 16x16x16 MFMA A-layout per key subtile
      float psum = 0.f;
      bf16x4 pa[4];
#pragma unroll
      for (int s = 0; s < 4; ++s) {
        float p0 = exp2f(sc[s][0] - mnew);
        float p1 = exp2f(sc[s][1] - mnew);
        float p2 = exp2f(sc[s][2] - mnew);
        float p3 = exp2f(sc[s][3] - mnew);
        psum += (p0 + p1) + (p2 + p3);
        pa[s][0] = (bf16_t)p0; pa[s][1] = (bf16_t)p1;
        pa[s][2] = (bf16_t)p2; pa[s][3] = (bf16_t)p3;
      }

      if (!defer) {
        const float alpha = exp2f(m - mnew);
        float al[4];
#pragma unroll
        for (int r = 0; r < 4; ++r) al[r] = __shfl(alpha, quad * 4 + r);
#pragma unroll
        for (int t2 = 0; t2 < 4; ++t2) {
          oacc[t2][0] *= al[0]; oacc[t2][1] *= al[1];
          oacc[t2][2] *= al[2]; oacc[t2][3] *= al[3];
        }
        l = l * alpha + psum;   // per-lane partial, column-uniform alpha
        m = mnew;
      } else {
        l += psum;
      }

      // O += P . V : K=16 MFMA per key subtile, V^T from swizzled LDS
      __builtin_amdgcn_s_setprio(1);
#pragma unroll
      for (int s = 0; s < 4; ++s) {
        const s16x4 pas = __builtin_bit_cast(s16x4, pa[s]);
        const int cA = 2 * s + (quad >> 1);   // tile-local 16B chunk of 8 keys
#pragma unroll
        for (int t2 = 0; t2 < 4; ++t2) {
          const int d = 16 * t2 + li;
          s16x4 vb = *(const s16x4*)(
              &v0[d * 64 + ((cA ^ lk) << 3) + (quad & 1) * 4]);
          oacc[t2] = __builtin_amdgcn_mfma_f32_16x16x16bf16_1k(pas, vb, oacc[t2], 0, 0, 0);
        }
      }
      __builtin_amdgcn_s_setprio(0);
    }

    // ---- counted-vmcnt barrier: never drain in-flight prefetches ----
    if (t + 1 < nt) {
      asm volatile("s_waitcnt lgkmcnt(0)" ::: "memory");
      if (t + 2 < nt) asm volatile("s_waitcnt vmcnt(4)" ::: "memory");
      else            asm volatile("s_waitcnt vmcnt(0)" ::: "memory");
      __builtin_amdgcn_s_barrier();
      __builtin_amdgcn_sched_barrier(0);
    }
    bf16_t* tk = k0; k0 = k1; k1 = k2; k2 = tk;
    bf16_t* tv = v0; v0 = v1; v1 = v2; v2 = tv;
  }

  // ---- epilogue: reduce the per-lane l partials, then normalize ----
  l += __shfl_xor(l, 16);
  l += __shfl_xor(l, 32);
  float rl[4];
#pragma unroll
  for (int r = 0; r < 4; ++r) {
    float lv = __shfl(l, quad * 4 + r);
    rl[r] = 1.0f / lv;
  }
  float* orow = outg + ((size_t)((b * SQ_ + q0) * NH_ + h)) * DH_;
#pragma unroll
  for (int t = 0; t < 4; ++t)
#pragma unroll
    for (int r = 0; r < 4; ++r)
      orow[(size_t)(quad * 4 + r) * (NH_ * DH_) + 16 * t + li] = oacc[t][r] * rl[r];
}

extern "C" void kernel_launch(void* const* d_in, const int* in_sizes, int n_in,
                              void* d_out, int out_size, void* d_ws, size_t ws_size,
                              hipStream_t stream) {
  (void)in_sizes; (void)n_in; (void)out_size; (void)ws_size;
  const float* q  = (const float*)d_in[0];
  const float* kv = (const float*)d_in[1];
  float* out = (float*)d_out;
  bf16_t* wse = (bf16_t*)d_ws;   // needs 16 MiB

  kv_prep<<<dim3(32 * 32), 256, 0, stream>>>(kv, wse);
  fa_fwd<<<dim3(B_ * NH_ * (SQ_ / 64)), 256, 0, stream>>>(q, wse, out);
}

// Round 10
// 122.927 us; speedup vs baseline: 1.0233x; 1.0003x over previous
//
#include <hip/hip_runtime.h>
#include <hip/hip_bf16.h>

#define B_    2
#define SQ_   2048
#define SK_   2048
#define NH_   16
#define DH_   64
#define WIN_  256
#define NEG_  -30000.0f

typedef __bf16 bf16_t;
typedef bf16_t bf16x8 __attribute__((ext_vector_type(8)));
typedef bf16_t bf16x4 __attribute__((ext_vector_type(4)));
typedef float  f32x4  __attribute__((ext_vector_type(4)));
typedef float  f32x16 __attribute__((ext_vector_type(16)));
typedef unsigned int u32;

// bf16 images in workspace, XOR swizzle baked into the GLOBAL layout
// (16B-chunk index ^= row&7), so tile staging is a linear global_load_lds copy
// and LDS reads apply the same XOR (T2 / m173 pattern):
//   K  [bh][key][d]: elem = bh*131072 + key*64 + ((c ^ (key&7))<<3) + (d&7)
//   V^T[bh][d][key]: elem = 4194304 + bh*131072 + d*2048
//                           + (((g&~7)|((g&7)^(d&7)))<<3) + (key&7),  g = key>>3
#define KE_BH 131072
#define VT_E  4194304
#define PSTRIDE 72

#define GLOAD_LDS16(g, l)                                                      \
  __builtin_amdgcn_global_load_lds(                                            \
      (const __attribute__((address_space(1))) u32*)(g),                       \
      (__attribute__((address_space(3))) u32*)(l), 16, 0, 0)

static __device__ __forceinline__ f32x16 zero16() {
  f32x16 z;
#pragma unroll
  for (int i = 0; i < 16; ++i) z[i] = 0.f;
  return z;
}

// ---------------- prep: f32 KV -> swizzled bf16 K / V^T images ----------------
// one block per (bh, 64-key tile); all global stores are 16B vectors
__global__ __launch_bounds__(256)
void kv_prep(const float* __restrict__ kvg, bf16_t* __restrict__ wse) {
  __shared__ __align__(16) bf16_t sT[4096];   // V^T tile, image layout
  const int tid = threadIdx.x;
  const int bb  = blockIdx.x;          // bh*32 + kt
  const int bh  = bb >> 5, kt = bb & 31;
  const int b   = bh >> 4, h = bh & 15;

  const int skey = tid >> 2;           // 0..63
  const int sd0  = (tid & 3) * 16;     // 0,16,32,48
  const int key  = kt * 64 + skey;

  const float* src =
      kvg + ((((size_t)b * SK_ + key) * 2) * NH_ + h) * (size_t)DH_ + sd0;
  f32x4 ka[4], va[4];
#pragma unroll
  for (int i = 0; i < 4; ++i) {
    ka[i] = *(const f32x4*)(src + 4 * i);
    va[i] = *(const f32x4*)(src + NH_ * DH_ + 4 * i);
  }

  // K: two swizzled 16B stores
  bf16_t* kdst = wse + (size_t)bh * KE_BH + (size_t)key * 64;
#pragma unroll
  for (int hh = 0; hh < 2; ++hh) {
    bf16x8 w;
#pragma unroll
    for (int i = 0; i < 4; ++i) {
      w[i] = (bf16_t)ka[2 * hh][i]; w[i + 4] = (bf16_t)ka[2 * hh + 1][i];
    }
    const int c = (sd0 >> 3) + hh;
    *(bf16x8*)(kdst + ((c ^ (key & 7)) << 3)) = w;
  }

  // V: transpose into LDS using the tile-local image layout
  const int g = skey >> 3, kw = skey & 7;
#pragma unroll
  for (int j = 0; j < 16; ++j) {
    const int d = sd0 + j;
    sT[d * 64 + ((g ^ (d & 7)) << 3) + kw] = (bf16_t)va[j >> 2][j & 3];
  }
  __syncthreads();

  // copy-out: 2 x 16B per thread, contiguous
  const int dr = tid >> 2, rp = (tid & 3) * 16;
  bf16_t* vdst = wse + VT_E + (size_t)bh * KE_BH + (size_t)dr * 2048 + kt * 64 + rp;
  *(bf16x8*)(vdst)     = *(const bf16x8*)(&sT[dr * 64 + rp]);
  *(bf16x8*)(vdst + 8) = *(const bf16x8*)(&sT[dr * 64 + rp + 8]);
}

// ------------------------------- main kernel ---------------------------------
// 4 waves x 32 q-rows (128/block), 32x32x16 MFMA, image tiles via global_load_lds
__global__ __launch_bounds__(256, 2)
void fa_fwd(const float* __restrict__ qg, const bf16_t* __restrict__ wse,
            float* __restrict__ outg) {
  const int tid  = threadIdx.x;
  const int wid  = tid >> 6;      // 0..3, each wave owns 32 q-rows
  const int lane = tid & 63;
  const int c31  = lane & 31;     // q-column within the wave's 32 rows
  const int hi   = lane >> 5;

  const int bid = blockIdx.x;
  const int qb  = bid >> 5;   // 16 q-blocks of 128 rows
  const int bh  = bid & 31;   // same bh -> same XCD (kv L2 locality)
  const int b   = bh >> 4;
  const int h   = bh & 15;

  const int q0b = qb * 128;
  const int q0  = q0b + wid * 32;

  __shared__ __align__(16) bf16_t sK[2][4096];      // K tile images (swizzled)
  __shared__ __align__(16) bf16_t sV[2][4096];      // V^T tile images (swizzled)
  __shared__ __align__(16) bf16_t sP[4][32 * PSTRIDE];  // per-wave P [q][key]
  bf16_t* plw = sP[wid];

  const bf16_t* kbh = wse + (size_t)bh * KE_BH;
  const bf16_t* vbh = wse + VT_E + (size_t)bh * KE_BH;

  // ---- Q fragments (32 rows, one q-col per lane), scale * log2(e) folded ----
  const float qscale = 0.125f * 1.44269504088896340736f;
  const float* qrow = qg + ((size_t)((b * SQ_ + q0 + c31) * NH_ + h)) * DH_;
  bf16x8 qfrag[4];   // B-operand: Q[q=c31][d = ds*16 + hi*8 + e]
#pragma unroll
  for (int ds = 0; ds < 4; ++ds) {
    const int d0 = ds * 16 + hi * 8;
    f32x4 a0 = *(const f32x4*)(qrow + d0);
    f32x4 a1 = *(const f32x4*)(qrow + d0 + 4);
#pragma unroll
    for (int i = 0; i < 4; ++i) {
      qfrag[ds][i]     = (bf16_t)(a0[i] * qscale);
      qfrag[ds][i + 4] = (bf16_t)(a1[i] * qscale);
    }
  }

  f32x16 oacc[2];   // O[q-rows (C layout)][d = dt*32 + c31]
  oacc[0] = zero16(); oacc[1] = zero16();
  float m = NEG_, el = 0.f;   // per-lane state for q-column c31 (hi-half partial)

  // block-uniform 64-aligned key range
  int klo = q0b - WIN_; if (klo < 0) klo = 0;
  int khi = q0b + 127 + WIN_ + 1; if (khi > SK_) khi = SK_;
  const int nt = (khi - klo + 63) >> 6;

  // staging: 4 x global_load_lds(16B) per thread per tile, lane-linear dests
  const int tid8 = tid * 8;
  const int vs0  = (tid >> 3) * 2048 + (tid & 7) * 8;

  auto stage_async = [&](int kt, bf16_t* kd, bf16_t* vd) {
    GLOAD_LDS16(kbh + kt * 64 + tid8,        kd + tid8);
    GLOAD_LDS16(kbh + kt * 64 + 2048 + tid8, kd + 2048 + tid8);
    GLOAD_LDS16(vbh + kt + vs0,              vd + tid8);
    GLOAD_LDS16(vbh + kt + vs0 + 65536,      vd + 2048 + tid8);
  };

  // ---- prologue: stage tile 0 -> buf 0; __syncthreads drains the DMA ----
  stage_async(klo, sK[0], sV[0]);
  __syncthreads();

  int buf = 0;
  for (int t = 0; t < nt; ++t) {
    const int kk = klo + t * 64;
    if (t + 1 < nt) stage_async(kk + 64, sK[buf ^ 1], sV[buf ^ 1]);

    // ---- compute only if this tile intersects the wave's window ----
    if (kk + 63 >= q0 - WIN_ && kk <= q0 + 31 + WIN_) {
      // S^T = K . Q^T : two 32-key halves, D=64 as four K=16 chunks
      f32x16 sc[2];
      __builtin_amdgcn_s_setprio(1);
#pragma unroll
      for (int kh = 0; kh < 2; ++kh) {
        const int key = kh * 32 + c31;
        const int sw  = key & 7;
        f32x16 acc = zero16();
#pragma unroll
        for (int ds = 0; ds < 4; ++ds) {
          bf16x8 kf = *(const bf16x8*)(
              &sK[buf][key * 64 + (((ds * 2 + hi) ^ sw) << 3)]);
          acc = __builtin_amdgcn_mfma_f32_32x32x16_bf16(kf, qfrag[ds], acc, 0, 0, 0);
        }
        sc[kh] = acc;
      }
      __builtin_amdgcn_s_setprio(0);

      // window mask only on boundary tiles (wave-uniform branch)
      if (kk < q0 - 225 || kk > q0 + 193) {
        const int qa = q0 + c31;
#pragma unroll
        for (int kh = 0; kh < 2; ++kh)
#pragma unroll
          for (int r = 0; r < 16; ++r) {
            int key = kk + kh * 32 + (r & 3) + 8 * (r >> 2) + 4 * hi;
            unsigned dd = (unsigned)(key - qa + WIN_);
            if (dd > 2u * WIN_) sc[kh][r] = NEG_;
          }
      }

      // local tile max for this lane's q-column (keys split across hi-halves;
      // the __all ballot covers both halves, so no reduce on the defer path)
      float tl = NEG_;
#pragma unroll
      for (int kh = 0; kh < 2; ++kh)
#pragma unroll
        for (int r = 0; r < 16; r += 4)
          tl = fmaxf(tl, fmaxf(fmaxf(sc[kh][r], sc[kh][r + 1]),
                               fmaxf(sc[kh][r + 2], sc[kh][r + 3])));

      const bool defer = (__all(tl <= m + 8.0f) != 0);   // wave-uniform
      float mnew = m;
      if (!defer) {
        float tr = fmaxf(tl, __shfl_xor(tl, 32));
        mnew = fmaxf(m, tr);
      }

      // exp + pack + write P to per-wave LDS [q][key]
      float psum = 0.f;
#pragma unroll
      for (int kh = 0; kh < 2; ++kh)
#pragma unroll
        for (int g = 0; g < 4; ++g) {
          float p0 = exp2f(sc[kh][4 * g + 0] - mnew);
          float p1 = exp2f(sc[kh][4 * g + 1] - mnew);
          float p2 = exp2f(sc[kh][4 * g + 2] - mnew);
          float p3 = exp2f(sc[kh][4 * g + 3] - mnew);
          psum += (p0 + p1) + (p2 + p3);
          bf16x4 pk;
          pk[0] = (bf16_t)p0; pk[1] = (bf16_t)p1;
          pk[2] = (bf16_t)p2; pk[3] = (bf16_t)p3;
          // C row = (reg&3)+8*(reg>>2)+4*hi -> keys g*8+hi*4+{0..3} consecutive
          *(bf16x4*)(&plw[c31 * PSTRIDE + kh * 32 + g * 8 + hi * 4]) = pk;
        }

      if (!defer) {
        const float alq = exp2f(m - mnew);   // per-lane (q=c31), halves identical
#pragma unroll
        for (int r = 0; r < 16; ++r) {
          const int row = (r & 3) + 8 * (r >> 2) + 4 * hi;
          const float al = __shfl(alq, row);
          oacc[0][r] *= al; oacc[1][r] *= al;
        }
        el = el * alq + psum;
        m = mnew;
      } else {
        el += psum;
      }

      // wave-local drain: sP round-trip is per-wave
      asm volatile("s_waitcnt lgkmcnt(0)" ::: "memory");

      // P A-fragments: P[q=c31][key = ks*16 + hi*8 + e]
      bf16x8 pf[4];
#pragma unroll
      for (int ks = 0; ks < 4; ++ks)
        pf[ks] = *(const bf16x8*)(&plw[c31 * PSTRIDE + ks * 16 + hi * 8]);

      // O += P . V : full-rate 32x32x16, V^T image from LDS (swizzled chunks)
      __builtin_amdgcn_s_setprio(1);
#pragma unroll
      for (int dt = 0; dt < 2; ++dt) {
        const int d  = dt * 32 + c31;
        const int sw = d & 7;
#pragma unroll
        for (int ks = 0; ks < 4; ++ks) {
          bf16x8 vf = *(const bf16x8*)(
              &sV[buf][d * 64 + (((ks * 2 + hi) ^ sw) << 3)]);
          oacc[dt] = __builtin_amdgcn_mfma_f32_32x32x16_bf16(pf[ks], vf, oacc[dt], 0, 0, 0);
        }
      }
      __builtin_amdgcn_s_setprio(0);
    }

    __syncthreads();   // single barrier: drains the async copies, flips buffers
    buf ^= 1;
  }

  // ---- epilogue: merge hi/lo halves of the denominator, normalize, store ----
  el += __shfl_xor(el, 32);
  const float rlq = 1.0f / el;   // for q-column c31
#pragma unroll
  for (int r = 0; r < 16; ++r) {
    const int row = (r & 3) + 8 * (r >> 2) + 4 * hi;
    const float rl = __shfl(rlq, row);
    float* orow = outg + ((size_t)((b * SQ_ + q0 + row) * NH_ + h)) * DH_;
#pragma unroll
    for (int dt = 0; dt < 2; ++dt)
      orow[dt * 32 + c31] = oacc[dt][r] * rl;
  }
}

extern "C" void kernel_launch(void* const* d_in, const int* in_sizes, int n_in,
                              void* d_out, int out_size, void* d_ws, size_t ws_size,
                              hipStream_t stream) {
  (void)in_sizes; (void)n_in; (void)out_size; (void)ws_size;
  const float* q  = (const float*)d_in[0];
  const float* kv = (const float*)d_in[1];
  float* out = (float*)d_out;
  bf16_t* wse = (bf16_t*)d_ws;   // needs 16 MiB

  kv_prep<<<dim3(32 * 32), 256, 0, stream>>>(kv, wse);
  fa_fwd<<<dim3(B_ * NH_ * (SQ_ / 128)), 256, 0, stream>>>(q, wse, out);
}